// Round 1
// 480.261 us; speedup vs baseline: 1.3499x; 1.3499x over previous
//
#include <hip/hip_runtime.h>

constexpr int TT = 512;    // timesteps
constexpr int BB = 256;    // batch
constexpr int HH = 128;    // hidden = embed
constexpr int VV = 32000;  // vocab

typedef _Float16 h2 __attribute__((ext_vector_type(2)));
typedef _Float16 f16x4 __attribute__((ext_vector_type(4)));
typedef _Float16 f16x8 __attribute__((ext_vector_type(8)));
typedef float f32x4 __attribute__((ext_vector_type(4)));

struct __align__(16) H2x4 { h2 a, b, c, d; };

__device__ __forceinline__ h2 pkrtz(float a, float b) {
  return __builtin_bit_cast(h2, __builtin_amdgcn_cvt_pkrtz(a, b));
}
__device__ __forceinline__ float fdot2(h2 a, h2 b, float c) {
  return __builtin_amdgcn_fdot2(a, b, c, false);
}
// quad_perm DPP: 0xB1 = lane^1, 0x4E = lane^2 (within each quad)
template <int CTRL>
__device__ __forceinline__ float qmov(float v) {
  return __builtin_bit_cast(
      float, __builtin_amdgcn_mov_dpp(__builtin_bit_cast(int, v), CTRL, 0xf,
                                      0xf, true));
}

// Pack all 4 gate weight matrices into Wct[n=4u+g][k] f16 (k 0..127 = e-part,
// k 128..255 = h-part) and bcat[n] = bias. Row n: gates interleaved per unit
// so that thread tid == column n in lstm_rec, and xch reads are contiguous.
__global__ __launch_bounds__(256, 4) void wprep(
    const float* __restrict__ Wi, const float* __restrict__ bi,
    const float* __restrict__ Wf, const float* __restrict__ bf,
    const float* __restrict__ Wc, const float* __restrict__ bc,
    const float* __restrict__ Wo, const float* __restrict__ bo,
    _Float16* __restrict__ Wct, float* __restrict__ bcat) {
  const int n = blockIdx.x;  // 0..511
  const int g = n & 3;
  const int u = n >> 2;
  const float* Wg = (g == 0) ? Wi : (g == 1) ? Wf : (g == 2) ? Wc : Wo;
  const float* bg = (g == 0) ? bi : (g == 1) ? bf : (g == 2) ? bc : bo;
  const int k = threadIdx.x;  // 0..255
  Wct[(size_t)n * 256 + k] = (_Float16)Wg[(size_t)k * HH + u];
  if (k == 0) bcat[n] = bg[u];
}

// One block per batch element (256 blocks), 512 threads = 8 waves.
// Thread map (recurrence): u = 16w + (l>>2), qk = l&3 = k-quarter AND own gate.
//   column n = 4u + qk = tid  (so xch[t][tid] is this thread's e-projection).
// Every 64 steps: MFMA e-projection phase computes xch[64][512] f16 in LDS
//   (bias folded), W e-frags register-resident (wfx, 64 VGPR), wave w owns
//   n-slice [64w, 64w+64).
// Recurrence step: 4 ds_read_b128 (own 32-k quarter of h), 64 fdot2 (4 gates),
//   quad DPP butterfly -> full 128-k sums on every lane, 1 transcendental pair
//   per lane (own gate), 3 DPP to share activations, state in regs.
//   ONE barrier per step.
__global__ __launch_bounds__(512, 2) void lstm_rec(
    const int* __restrict__ x, const float* __restrict__ emb,
    const _Float16* __restrict__ Wct, const float* __restrict__ bcat,
    _Float16* __restrict__ hbf) {
  const int b = blockIdx.x;
  const int tid = threadIdx.x;
  const int w = tid >> 6;
  const int l = tid & 63;
  const int qk = l & 3;            // k-quarter and own gate (0=i,1=f,2=c,3=o)
  const int u = 16 * w + (l >> 2); // unit
  const int n16 = l & 15;
  const int quad = l >> 4;

  __shared__ int xrow[TT];
  __shared__ __align__(16) _Float16 comb[2][HH];   // h double-buffer
  __shared__ __align__(16) _Float16 xch[64][514];  // e-proj chunk, pad 2

  xrow[tid] = x[(size_t)b * TT + tid];
  if (tid < HH) comb[0][tid] = (_Float16)0.f;

  // ---- h-part weights: wr2[g][i] = {Wg[128+32qk+2i][u], Wg[128+32qk+2i+1][u]}
  h2 wr2[4][16];
#pragma unroll
  for (int g = 0; g < 4; ++g) {
    const _Float16* wp = Wct + (size_t)(4 * u + g) * 256 + 128 + 32 * qk;
#pragma unroll
    for (int j = 0; j < 4; ++j) {
      const H2x4 q = __builtin_bit_cast(H2x4, *(const f16x8*)(wp + 8 * j));
      wr2[g][4 * j + 0] = q.a;
      wr2[g][4 * j + 1] = q.b;
      wr2[g][4 * j + 2] = q.c;
      wr2[g][4 * j + 3] = q.d;
    }
  }

  // ---- e-part W frags (MFMA A-operand) + bias, register-resident
  f16x8 wfx[4][4];
  f32x4 biasr[4];
#pragma unroll
  for (int nt = 0; nt < 4; ++nt) {
#pragma unroll
    for (int ks = 0; ks < 4; ++ks)
      wfx[nt][ks] = *(const f16x8*)(Wct +
                                    (size_t)(64 * w + nt * 16 + n16) * 256 +
                                    ks * 32 + quad * 8);
    biasr[nt] = *(const f32x4*)(bcat + 64 * w + nt * 16 + quad * 4);
  }

  // per-lane activation constants: sigmoid r=1/(1+e^-a); tanh 1-2/(e^2a+1)
  const bool isc = (qk == 2);
  const float k1 = isc ? 2.f : -1.f;
  const float gam = isc ? -2.f : 1.f;
  const float del = isc ? 1.f : 0.f;

  float cst = 0.f;
  float hv = 0.f;
  int buf = 0;

  __syncthreads();  // xrow + comb[0] visible

  for (int c = 0; c < 8; ++c) {
    // ---- MFMA e-projection for t in [64c, 64c+64): xch[t&63][n], bias folded
    // D[n][t]: A = Wct e-part rows n (k-contig), B = gathered emb cols t.
#pragma unroll 2
    for (int tt = 0; tt < 4; ++tt) {
      const int vid = xrow[c * 64 + tt * 16 + n16];
      const float* ep = emb + (size_t)vid * HH + quad * 8;
      f16x8 ef[4];
#pragma unroll
      for (int ks = 0; ks < 4; ++ks) {
        const float4 e0 = *(const float4*)(ep + ks * 32);
        const float4 e1 = *(const float4*)(ep + ks * 32 + 4);
        H2x4 q;
        q.a = pkrtz(e0.x, e0.y);
        q.b = pkrtz(e0.z, e0.w);
        q.c = pkrtz(e1.x, e1.y);
        q.d = pkrtz(e1.z, e1.w);
        ef[ks] = __builtin_bit_cast(f16x8, q);
      }
      f32x4 acc[4] = {};
#pragma unroll
      for (int ks = 0; ks < 4; ++ks)
#pragma unroll
        for (int nt = 0; nt < 4; ++nt)
          acc[nt] = __builtin_amdgcn_mfma_f32_16x16x32_f16(wfx[nt][ks], ef[ks],
                                                           acc[nt], 0, 0, 0);
#pragma unroll
      for (int nt = 0; nt < 4; ++nt) {
        const f32x4 av = acc[nt] + biasr[nt];
        _Float16* dst = &xch[tt * 16 + n16][64 * w + nt * 16 + quad * 4];
        *(h2*)dst = pkrtz(av[0], av[1]);
        *(h2*)(dst + 2) = pkrtz(av[2], av[3]);
      }
    }
    __syncthreads();  // xch ready

    // ---- 64 recurrence steps
#pragma unroll 2
    for (int tl = 0; tl < 64; ++tl) {
      const float xev = (float)xch[tl][tid];
      const _Float16* cb = &comb[buf][32 * qk];
      const H2x4 q0 = __builtin_bit_cast(H2x4, *(const f16x8*)(cb));
      const H2x4 q1 = __builtin_bit_cast(H2x4, *(const f16x8*)(cb + 8));
      const H2x4 q2 = __builtin_bit_cast(H2x4, *(const f16x8*)(cb + 16));
      const H2x4 q3 = __builtin_bit_cast(H2x4, *(const f16x8*)(cb + 24));
      float s0 = 0.f, s1 = 0.f, s2 = 0.f, s3 = 0.f;
#define DOT16(sg, g)                  \
  sg = fdot2(q0.a, wr2[g][0], sg);    \
  sg = fdot2(q0.b, wr2[g][1], sg);    \
  sg = fdot2(q0.c, wr2[g][2], sg);    \
  sg = fdot2(q0.d, wr2[g][3], sg);    \
  sg = fdot2(q1.a, wr2[g][4], sg);    \
  sg = fdot2(q1.b, wr2[g][5], sg);    \
  sg = fdot2(q1.c, wr2[g][6], sg);    \
  sg = fdot2(q1.d, wr2[g][7], sg);    \
  sg = fdot2(q2.a, wr2[g][8], sg);    \
  sg = fdot2(q2.b, wr2[g][9], sg);    \
  sg = fdot2(q2.c, wr2[g][10], sg);   \
  sg = fdot2(q2.d, wr2[g][11], sg);   \
  sg = fdot2(q3.a, wr2[g][12], sg);   \
  sg = fdot2(q3.b, wr2[g][13], sg);   \
  sg = fdot2(q3.c, wr2[g][14], sg);   \
  sg = fdot2(q3.d, wr2[g][15], sg);
      DOT16(s0, 0)
      DOT16(s1, 1)
      DOT16(s2, 2)
      DOT16(s3, 3)
#undef DOT16
      // quad butterfly: full 128-k sums of all 4 gates on every lane
      s0 += qmov<0xB1>(s0);
      s1 += qmov<0xB1>(s1);
      s2 += qmov<0xB1>(s2);
      s3 += qmov<0xB1>(s3);
      s0 += qmov<0x4E>(s0);
      s1 += qmov<0x4E>(s1);
      s2 += qmov<0x4E>(s2);
      s3 += qmov<0x4E>(s3);
      const float aown =
          (qk == 0 ? s0 : qk == 1 ? s1 : qk == 2 ? s2 : s3) + xev;
      // own-gate activation (1 exp + 1 div per lane)
      const float ex = __expf(k1 * aown);
      const float act = gam / (1.f + ex) + del;
      // share activations across the quad
      const float ax1 = qmov<0xB1>(act);
      const float va = (qk & 1) ? ax1 : act;  // even gate of own pair
      const float vb = (qk & 1) ? act : ax1;  // odd gate of own pair
      const float vax = qmov<0x4E>(va);
      const float vbx = qmov<0x4E>(vb);
      const float gi = (qk & 2) ? vax : va;
      const float gf = (qk & 2) ? vbx : vb;
      const float gc = (qk & 2) ? va : vax;
      const float go = (qk & 2) ? vb : vbx;
      cst = gf * cst + gi * gc;  // identical on all 4 quad lanes
      const float th = 1.f - 2.f / (__expf(2.f * cst) + 1.f);
      hv = go * th;
      if (qk == 0) comb[buf ^ 1][u] = (_Float16)hv;
      __syncthreads();  // h(t) visible; everyone done reading comb[buf]
      buf ^= 1;
    }
  }
  if (qk == 0) hbf[(size_t)b * HH + u] = (_Float16)hv;
}

// Wout[k][v] fp32 -> Wt[v][k] fp16 (coalesced loads across lanes=v).
__global__ __launch_bounds__(256, 4) void wout_tr(const float* __restrict__ Wout,
                                                  _Float16* __restrict__ Wt) {
  const int v = blockIdx.x * 256 + threadIdx.x;
#pragma unroll 1
  for (int kc = 0; kc < 16; ++kc) {
    float f[8];
#pragma unroll
    for (int i = 0; i < 8; ++i) f[i] = Wout[(size_t)(kc * 8 + i) * VV + v];
    H2x4 q;
    q.a = pkrtz(f[0], f[1]);
    q.b = pkrtz(f[2], f[3]);
    q.c = pkrtz(f[4], f[5]);
    q.d = pkrtz(f[6], f[7]);
    *(H2x4*)(Wt + (size_t)v * HH + kc * 8) = q;
  }
}

// logits = h @ Wout + bout via f16 MFMA, register-only.
// Block: 4 waves; tile [64 bat x 128 v]; wave: [64 bat x 32 v].
__global__ __launch_bounds__(256, 4) void lstm_out(
    const _Float16* __restrict__ Wt, const _Float16* __restrict__ hbf,
    const float* __restrict__ bout, float* __restrict__ out) {
  const int tid = threadIdx.x;
  const int wv = tid >> 6;
  const int lane = tid & 63;
  const int vblk = blockIdx.x % 250;
  const int batblk = blockIdx.x / 250;
  const int n16 = lane & 15;
  const int quad = lane >> 4;
  const int vbase = vblk * 128 + wv * 32;
  const int batbase = batblk * 64;

  f32x4 acc[4][2] = {};
#pragma unroll
  for (int ks = 0; ks < 4; ++ks) {
    const int k = ks * 32 + quad * 8;
    f16x8 a[4], bf_[2];
#pragma unroll
    for (int mt = 0; mt < 4; ++mt)
      a[mt] = *(const f16x8*)(hbf + (size_t)(batbase + mt * 16 + n16) * HH + k);
#pragma unroll
    for (int vt = 0; vt < 2; ++vt)
      bf_[vt] = *(const f16x8*)(Wt + (size_t)(vbase + vt * 16 + n16) * HH + k);
#pragma unroll
    for (int mt = 0; mt < 4; ++mt)
#pragma unroll
      for (int vt = 0; vt < 2; ++vt)
        acc[mt][vt] = __builtin_amdgcn_mfma_f32_16x16x32_f16(a[mt], bf_[vt],
                                                             acc[mt][vt], 0, 0, 0);
  }
#pragma unroll
  for (int vt = 0; vt < 2; ++vt) {
    const int v = vbase + vt * 16 + n16;
    const float bv = bout[v];
#pragma unroll
    for (int mt = 0; mt < 4; ++mt) {
#pragma unroll
      for (int r = 0; r < 4; ++r) {
        const int bat = batbase + mt * 16 + quad * 4 + r;
        out[(size_t)bat * VV + v] = acc[mt][vt][r] + bv;
      }
    }
  }
}

extern "C" void kernel_launch(void* const* d_in, const int* in_sizes, int n_in,
                              void* d_out, int out_size, void* d_ws,
                              size_t ws_size, hipStream_t stream) {
  const int* x = (const int*)d_in[0];
  const float* emb = (const float*)d_in[1];
  const float* Wi = (const float*)d_in[2];
  const float* bi = (const float*)d_in[3];
  const float* Wf = (const float*)d_in[4];
  const float* bf = (const float*)d_in[5];
  const float* Wc = (const float*)d_in[6];
  const float* bc = (const float*)d_in[7];
  const float* Wo = (const float*)d_in[8];
  const float* bo = (const float*)d_in[9];
  const float* Wout = (const float*)d_in[10];
  const float* bout = (const float*)d_in[11];
  float* out = (float*)d_out;

  _Float16* Wt = (_Float16*)d_ws;          // 32000*128 f16 = 8.192 MB
  _Float16* hbf = Wt + (size_t)VV * HH;    // 256*128 f16  = 64 KB
  _Float16* Wct = hbf + (size_t)BB * HH;   // 512*256 f16  = 256 KB
  float* bcat = (float*)(Wct + 512 * 256); // 512 f32      = 2 KB

  wprep<<<512, 256, 0, stream>>>(Wi, bi, Wf, bf, Wc, bc, Wo, bo, Wct, bcat);
  wout_tr<<<VV / 256, 256, 0, stream>>>(Wout, Wt);
  lstm_rec<<<BB, 512, 0, stream>>>(x, emb, Wct, bcat, hbf);
  lstm_out<<<(VV / 128) * (BB / 64), 256, 0, stream>>>(Wt, hbf, bout, out);
}

// Round 2
// 426.216 us; speedup vs baseline: 1.5210x; 1.1268x over previous
//
#include <hip/hip_runtime.h>

constexpr int TT = 512;    // timesteps
constexpr int BB = 256;    // batch
constexpr int HH = 128;    // hidden = embed
constexpr int VV = 32000;  // vocab

typedef _Float16 h2 __attribute__((ext_vector_type(2)));
typedef _Float16 f16x4 __attribute__((ext_vector_type(4)));
typedef _Float16 f16x8 __attribute__((ext_vector_type(8)));
typedef float f32x4 __attribute__((ext_vector_type(4)));

struct __align__(16) H2x4 { h2 a, b, c, d; };

__device__ __forceinline__ h2 pkrtz(float a, float b) {
  return __builtin_bit_cast(h2, __builtin_amdgcn_cvt_pkrtz(a, b));
}
__device__ __forceinline__ float fexp2(float x) {
  return __builtin_amdgcn_exp2f(x);
}
__device__ __forceinline__ float frcp(float x) {
  return __builtin_amdgcn_rcpf(x);
}

// log2(e) and 2*log2(e): gate pre-scales so activations are exp2-direct.
//   g in {i,f,o}: a = -x*log2e  -> exp2(a) = e^-x   (sigmoid)
//   g == c      : a = 2x*log2e  -> exp2(a) = e^{2x} (tanh)
constexpr float SC_SIG = -1.4426950408889634f;
constexpr float SC_TANH = 2.8853900817779268f;

// Pack all 4 gate weight matrices into Wct[n=4u+g][k] f16 (k 0..127 = e-part,
// k 128..255 = h-part) and bcat[n] = bias, with the gate activation scale
// folded in. Row n: gates interleaved per unit (n = 4u+g).
__global__ __launch_bounds__(256, 4) void wprep(
    const float* __restrict__ Wi, const float* __restrict__ bi,
    const float* __restrict__ Wf, const float* __restrict__ bf,
    const float* __restrict__ Wc, const float* __restrict__ bc,
    const float* __restrict__ Wo, const float* __restrict__ bo,
    _Float16* __restrict__ Wct, float* __restrict__ bcat) {
  const int n = blockIdx.x;  // 0..511
  const int g = n & 3;
  const int u = n >> 2;
  const float* Wg = (g == 0) ? Wi : (g == 1) ? Wf : (g == 2) ? Wc : Wo;
  const float* bg = (g == 0) ? bi : (g == 1) ? bf : (g == 2) ? bc : bo;
  const float sc = (g == 2) ? SC_TANH : SC_SIG;
  const int k = threadIdx.x;  // 0..255
  Wct[(size_t)n * 256 + k] = (_Float16)(Wg[(size_t)k * HH + u] * sc);
  if (k == 0) bcat[n] = bg[u] * sc;
}

// One block per batch element (256 blocks), 512 threads = 8 waves.
// Every 64 steps: MFMA e-projection phase computes xch[64][512] f16 in LDS
//   (scaled bias folded), wave w owns n-slice [64w, 64w+64).
// Recurrence step (the new part): h-dots on the MFMA pipe.
//   B = h(t-1) broadcast into all 16 cols (wave-uniform ds_read_b128).
//   A = W h-part rows (wh frags, register-resident).
//   D[n][*]: every lane holds ALL 4 gates of unit u = 16w + 4*(n16&3) + quad
//   in acc[nt = n16&3][g]. Select 1 of 4 nt slabs (12 cndmask), add e-proj,
//   activate with exp2+rcp (weights pre-scaled), cst per-lane (4x dup).
//   No cross-lane ops, ONE barrier per step, VALU ~45 inst/step.
__global__ __launch_bounds__(512, 2) void lstm_rec(
    const int* __restrict__ x, const float* __restrict__ emb,
    const _Float16* __restrict__ Wct, const float* __restrict__ bcat,
    _Float16* __restrict__ hbf) {
  const int b = blockIdx.x;
  const int tid = threadIdx.x;
  const int w = tid >> 6;
  const int l = tid & 63;
  const int n16 = l & 15;
  const int quad = l >> 4;
  const int nts = n16 & 3;                 // which nt slab this lane activates
  const int u = 16 * w + 4 * nts + quad;   // unit this lane owns

  __shared__ int xrow[TT];
  __shared__ __align__(16) _Float16 comb[2][HH];   // h double-buffer
  __shared__ __align__(16) _Float16 xch[64][516];  // e-proj chunk (8B rows)

  xrow[tid] = x[(size_t)b * TT + tid];
  if (tid < HH) comb[0][tid] = (_Float16)0.f;

  // ---- h-part A-frags: wh[nt][ks] = W[n=64w+nt*16+n16][128+ks*32+quad*8..+7]
  f16x8 wh[4][4];
#pragma unroll
  for (int nt = 0; nt < 4; ++nt)
#pragma unroll
    for (int ks = 0; ks < 4; ++ks)
      wh[nt][ks] = *(const f16x8*)(Wct +
                                   (size_t)(64 * w + nt * 16 + n16) * 256 +
                                   128 + ks * 32 + quad * 8);

  // ---- e-part A-frags (MFMA A-operand) + scaled bias, register-resident
  f16x8 wfx[4][4];
  f32x4 biasr[4];
#pragma unroll
  for (int nt = 0; nt < 4; ++nt) {
#pragma unroll
    for (int ks = 0; ks < 4; ++ks)
      wfx[nt][ks] = *(const f16x8*)(Wct +
                                    (size_t)(64 * w + nt * 16 + n16) * 256 +
                                    ks * 32 + quad * 8);
    biasr[nt] = *(const f32x4*)(bcat + 64 * w + nt * 16 + quad * 4);
  }

  float cst = 0.f;
  float hv = 0.f;
  int buf = 0;

  __syncthreads();  // xrow + comb[0] visible

  for (int c = 0; c < 8; ++c) {
    // ---- MFMA e-projection for t in [64c, 64c+64): xch[t&63][n], bias folded
#pragma unroll 2
    for (int tt = 0; tt < 4; ++tt) {
      const int vid = xrow[c * 64 + tt * 16 + n16];
      const float* ep = emb + (size_t)vid * HH + quad * 8;
      f16x8 ef[4];
#pragma unroll
      for (int ks = 0; ks < 4; ++ks) {
        const float4 e0 = *(const float4*)(ep + ks * 32);
        const float4 e1 = *(const float4*)(ep + ks * 32 + 4);
        H2x4 q;
        q.a = pkrtz(e0.x, e0.y);
        q.b = pkrtz(e0.z, e0.w);
        q.c = pkrtz(e1.x, e1.y);
        q.d = pkrtz(e1.z, e1.w);
        ef[ks] = __builtin_bit_cast(f16x8, q);
      }
      f32x4 acc[4] = {};
#pragma unroll
      for (int ks = 0; ks < 4; ++ks)
#pragma unroll
        for (int nt = 0; nt < 4; ++nt)
          acc[nt] = __builtin_amdgcn_mfma_f32_16x16x32_f16(wfx[nt][ks], ef[ks],
                                                           acc[nt], 0, 0, 0);
#pragma unroll
      for (int nt = 0; nt < 4; ++nt) {
        const f32x4 av = acc[nt] + biasr[nt];
        _Float16* dst = &xch[tt * 16 + n16][64 * w + nt * 16 + quad * 4];
        *(h2*)dst = pkrtz(av[0], av[1]);
        *(h2*)(dst + 2) = pkrtz(av[2], av[3]);
      }
    }
    __syncthreads();  // xch ready

    // ---- 64 recurrence steps
#pragma unroll 2
    for (int tl = 0; tl < 64; ++tl) {
      // own-unit e-projection (4 gates), independent of h: issue early
      const f16x4 xe4 = *(const f16x4*)(&xch[tl][4 * u]);

      // B frags: h(t-1) broadcast to all 16 cols (wave-uniform reads)
      const _Float16* cb = comb[buf];
      f16x8 hb[4];
#pragma unroll
      for (int ks = 0; ks < 4; ++ks)
        hb[ks] = *(const f16x8*)(cb + ks * 32 + quad * 8);

      f32x4 acc[4] = {};
#pragma unroll
      for (int ks = 0; ks < 4; ++ks)
#pragma unroll
        for (int nt = 0; nt < 4; ++nt)
          acc[nt] = __builtin_amdgcn_mfma_f32_16x16x32_f16(wh[nt][ks], hb[ks],
                                                           acc[nt], 0, 0, 0);

      // select this lane's nt slab: 12 cndmask
      const bool s1 = (n16 & 1) != 0;
      const bool s2 = (n16 & 2) != 0;
      const f32x4 t01 = s1 ? acc[1] : acc[0];
      const f32x4 t23 = s1 ? acc[3] : acc[2];
      const f32x4 av = s2 ? t23 : t01;

      const float a0 = av[0] + (float)xe4[0];  // i (scaled)
      const float a1 = av[1] + (float)xe4[1];  // f
      const float a2 = av[2] + (float)xe4[2];  // c
      const float a3 = av[3] + (float)xe4[3];  // o

      const float ei = fexp2(a0);
      const float ef_ = fexp2(a1);
      const float ec = fexp2(a2);
      const float eo = fexp2(a3);
      const float gi = frcp(1.f + ei);
      const float gf = frcp(1.f + ef_);
      const float gc = 1.f - 2.f * frcp(1.f + ec);
      const float go = frcp(1.f + eo);
      cst = gf * cst + gi * gc;
      const float th = 1.f - 2.f * frcp(1.f + fexp2(cst * SC_TANH));
      hv = go * th;

      if (n16 < 4) comb[buf ^ 1][u] = (_Float16)hv;
      __syncthreads();  // h(t) visible; all reads of comb[buf] done
      buf ^= 1;
    }
  }
  if (n16 < 4) hbf[(size_t)b * HH + u] = (_Float16)hv;
}

// Wout[k][v] fp32 -> Wt[v][k] fp16 (coalesced loads across lanes=v).
__global__ __launch_bounds__(256, 4) void wout_tr(const float* __restrict__ Wout,
                                                  _Float16* __restrict__ Wt) {
  const int v = blockIdx.x * 256 + threadIdx.x;
#pragma unroll 1
  for (int kc = 0; kc < 16; ++kc) {
    float f[8];
#pragma unroll
    for (int i = 0; i < 8; ++i) f[i] = Wout[(size_t)(kc * 8 + i) * VV + v];
    H2x4 q;
    q.a = pkrtz(f[0], f[1]);
    q.b = pkrtz(f[2], f[3]);
    q.c = pkrtz(f[4], f[5]);
    q.d = pkrtz(f[6], f[7]);
    *(H2x4*)(Wt + (size_t)v * HH + kc * 8) = q;
  }
}

// logits = h @ Wout + bout via f16 MFMA, register-only.
// Block: 4 waves; tile [64 bat x 128 v]; wave: [64 bat x 32 v].
__global__ __launch_bounds__(256, 4) void lstm_out(
    const _Float16* __restrict__ Wt, const _Float16* __restrict__ hbf,
    const float* __restrict__ bout, float* __restrict__ out) {
  const int tid = threadIdx.x;
  const int wv = tid >> 6;
  const int lane = tid & 63;
  const int vblk = blockIdx.x % 250;
  const int batblk = blockIdx.x / 250;
  const int n16 = lane & 15;
  const int quad = lane >> 4;
  const int vbase = vblk * 128 + wv * 32;
  const int batbase = batblk * 64;

  f32x4 acc[4][2] = {};
#pragma unroll
  for (int ks = 0; ks < 4; ++ks) {
    const int k = ks * 32 + quad * 8;
    f16x8 a[4], bf_[2];
#pragma unroll
    for (int mt = 0; mt < 4; ++mt)
      a[mt] = *(const f16x8*)(hbf + (size_t)(batbase + mt * 16 + n16) * HH + k);
#pragma unroll
    for (int vt = 0; vt < 2; ++vt)
      bf_[vt] = *(const f16x8*)(Wt + (size_t)(vbase + vt * 16 + n16) * HH + k);
#pragma unroll
    for (int mt = 0; mt < 4; ++mt)
#pragma unroll
      for (int vt = 0; vt < 2; ++vt)
        acc[mt][vt] = __builtin_amdgcn_mfma_f32_16x16x32_f16(a[mt], bf_[vt],
                                                             acc[mt][vt], 0, 0, 0);
  }
#pragma unroll
  for (int vt = 0; vt < 2; ++vt) {
    const int v = vbase + vt * 16 + n16;
    const float bv = bout[v];
#pragma unroll
    for (int mt = 0; mt < 4; ++mt) {
#pragma unroll
      for (int r = 0; r < 4; ++r) {
        const int bat = batbase + mt * 16 + quad * 4 + r;
        out[(size_t)bat * VV + v] = acc[mt][vt][r] + bv;
      }
    }
  }
}

extern "C" void kernel_launch(void* const* d_in, const int* in_sizes, int n_in,
                              void* d_out, int out_size, void* d_ws,
                              size_t ws_size, hipStream_t stream) {
  const int* x = (const int*)d_in[0];
  const float* emb = (const float*)d_in[1];
  const float* Wi = (const float*)d_in[2];
  const float* bi = (const float*)d_in[3];
  const float* Wf = (const float*)d_in[4];
  const float* bf = (const float*)d_in[5];
  const float* Wc = (const float*)d_in[6];
  const float* bc = (const float*)d_in[7];
  const float* Wo = (const float*)d_in[8];
  const float* bo = (const float*)d_in[9];
  const float* Wout = (const float*)d_in[10];
  const float* bout = (const float*)d_in[11];
  float* out = (float*)d_out;

  _Float16* Wt = (_Float16*)d_ws;          // 32000*128 f16 = 8.192 MB
  _Float16* hbf = Wt + (size_t)VV * HH;    // 256*128 f16  = 64 KB
  _Float16* Wct = hbf + (size_t)BB * HH;   // 512*256 f16  = 256 KB
  float* bcat = (float*)(Wct + 512 * 256); // 512 f32      = 2 KB

  wprep<<<512, 256, 0, stream>>>(Wi, bi, Wf, bf, Wc, bc, Wo, bo, Wct, bcat);
  wout_tr<<<VV / 256, 256, 0, stream>>>(Wout, Wt);
  lstm_rec<<<BB, 512, 0, stream>>>(x, emb, Wct, bcat, hbf);
  lstm_out<<<(VV / 128) * (BB / 64), 256, 0, stream>>>(Wt, hbf, bout, out);
}